// Round 1
// baseline (8987.473 us; speedup 1.0000x reference)
//
#include <hip/hip_runtime.h>
#include <math.h>

#define EPSF     0.1f
#define INV_EPS  10.0f
#define BB       8
#define NN       2048
#define DIM      32
#define MAX_ITER 100
#define THRESHF  0.1f
#define NSLOT    64

// dist[b,i,j] = sum_d (A[b,i,d] - Bv[b,j,d])^2  — called twice (x,y)->C, (y,x)->CT
__global__ __launch_bounds__(256) void sq_dist_kernel(const float* __restrict__ A,
                                                      const float* __restrict__ Bv,
                                                      float* __restrict__ Out) {
  const int b  = blockIdx.z;
  const int i0 = blockIdx.y * 16;
  const int j0 = blockIdx.x * 64;
  __shared__ float xs[16 * DIM];
  __shared__ float ys[64 * (DIM + 1)];   // +1 pad: breaks stride-32 bank conflict
  const int t = threadIdx.x;
#pragma unroll
  for (int rep = 0; rep < 2; rep++) {
    int id = t + rep * 256;
    int r = id >> 5, d = id & 31;
    xs[id] = A[((size_t)b * NN + i0 + r) * DIM + d];
  }
#pragma unroll
  for (int rep = 0; rep < 8; rep++) {
    int id = t + rep * 256;
    int r = id >> 5, d = id & 31;
    ys[r * (DIM + 1) + d] = Bv[((size_t)b * NN + j0 + r) * DIM + d];
  }
  __syncthreads();
  const int jl = t & 63;
  const int isub = t >> 6;
#pragma unroll
  for (int p = 0; p < 4; p++) {
    const int il = isub * 4 + p;
    float acc = 0.f;
#pragma unroll
    for (int d = 0; d < DIM; d++) {
      float df = xs[il * DIM + d] - ys[jl * (DIM + 1) + d];
      acc = fmaf(df, df, acc);
    }
    Out[((size_t)b * NN + i0 + il) * NN + j0 + jl] = acc;
  }
}

// One wave per row of Mat. self_i = cst - EPS * LSE_j((other_j - Mat[i,j])/EPS).
// IS_ROW: also accumulate err slots. !IS_ROW: WG(0,0) t0 reduces err -> done[iter+1].
template <bool IS_ROW>
__global__ __launch_bounds__(256) void dual_update(const float* __restrict__ Mat,
                                                   const float* __restrict__ other,
                                                   float* __restrict__ self,
                                                   float* __restrict__ errSlots,
                                                   int* __restrict__ doneArr,
                                                   int iter, float cst) {
  if (!IS_ROW) {
    if (blockIdx.x == 0 && blockIdx.y == 0 && threadIdx.x == 0) {
      float e = 0.f;
      for (int s = 0; s < NSLOT; s++) e += errSlots[iter * NSLOT + s];
      int dprev = doneArr[iter];
      doneArr[iter + 1] = (dprev || (e * 0.125f < THRESHF)) ? 1 : 0;
    }
  }
  if (doneArr[iter]) return;   // frozen: reference's where(done, old, new)

  const int b    = blockIdx.y;
  const int lane = threadIdx.x & 63;
  const int wave = threadIdx.x >> 6;
  const int i    = blockIdx.x * 4 + wave;
  const float* mrow = Mat + ((size_t)b * NN + i) * NN;
  const float* oth  = other + b * NN;

  float tv[32];
  float m = -INFINITY;
#pragma unroll
  for (int k = 0; k < 8; k++) {
    const int j = k * 256 + lane * 4;
    const float4 c4 = *(const float4*)(mrow + j);
    const float4 o4 = *(const float4*)(oth + j);
    float t0 = (o4.x - c4.x) * INV_EPS;
    float t1 = (o4.y - c4.y) * INV_EPS;
    float t2 = (o4.z - c4.z) * INV_EPS;
    float t3 = (o4.w - c4.w) * INV_EPS;
    tv[4 * k + 0] = t0; tv[4 * k + 1] = t1; tv[4 * k + 2] = t2; tv[4 * k + 3] = t3;
    m = fmaxf(m, fmaxf(fmaxf(t0, t1), fmaxf(t2, t3)));
  }
#pragma unroll
  for (int off = 32; off > 0; off >>= 1) m = fmaxf(m, __shfl_xor(m, off, 64));
  float s = 0.f;
#pragma unroll
  for (int k = 0; k < 32; k++) s += __expf(tv[k] - m);
#pragma unroll
  for (int off = 32; off > 0; off >>= 1) s += __shfl_xor(s, off, 64);

  if (IS_ROW) {
    __shared__ float du_sh[4];
    if (lane == 0) {
      float lse  = m + __logf(s);
      float unew = cst - EPSF * lse;
      float uold = self[b * NN + i];
      self[b * NN + i] = unew;
      du_sh[wave] = fabsf(unew - uold);
    }
    __syncthreads();
    if (threadIdx.x == 0) {
      atomicAdd(&errSlots[iter * NSLOT + (blockIdx.x & (NSLOT - 1))],
                du_sh[0] + du_sh[1] + du_sh[2] + du_sh[3]);
    }
  } else {
    if (lane == 0) {
      float lse = m + __logf(s);
      self[b * NN + i] = cst - EPSF * lse;
    }
  }
}

// pi = exp((u_i + v_j - C)/EPS); cost[b] = sum pi*C. Tile 64x64 per WG.
__global__ __launch_bounds__(256) void finalize_kernel(const float* __restrict__ C,
                                                       const float* __restrict__ u,
                                                       const float* __restrict__ v,
                                                       float* __restrict__ pi,
                                                       float* __restrict__ cost) {
  const int b  = blockIdx.z;
  const int i0 = blockIdx.y * 64, j0 = blockIdx.x * 64;
  const int t  = threadIdx.x;
  const int rr = t >> 4;
  const int cc = (t & 15) << 2;
  const float4 v4 = *(const float4*)(v + b * NN + j0 + cc);
  float local = 0.f;
#pragma unroll
  for (int q = 0; q < 4; q++) {
    const int i = i0 + rr + q * 16;
    const size_t base = ((size_t)b * NN + i) * NN + j0 + cc;
    const float4 c4 = *(const float4*)(C + base);
    const float uu = u[b * NN + i];
    float4 p4;
    p4.x = __expf((uu + v4.x - c4.x) * INV_EPS);
    p4.y = __expf((uu + v4.y - c4.y) * INV_EPS);
    p4.z = __expf((uu + v4.z - c4.z) * INV_EPS);
    p4.w = __expf((uu + v4.w - c4.w) * INV_EPS);
    *(float4*)(pi + base) = p4;
    local += p4.x * c4.x + p4.y * c4.y + p4.z * c4.z + p4.w * c4.w;
  }
#pragma unroll
  for (int off = 32; off > 0; off >>= 1) local += __shfl_xor(local, off, 64);
  __shared__ float red[4];
  if ((t & 63) == 0) red[t >> 6] = local;
  __syncthreads();
  if (t == 0) atomicAdd(&cost[b], red[0] + red[1] + red[2] + red[3]);
}

extern "C" void kernel_launch(void* const* d_in, const int* in_sizes, int n_in,
                              void* d_out, int out_size, void* d_ws, size_t ws_size,
                              hipStream_t stream) {
  const float* x = (const float*)d_in[0];
  const float* y = (const float*)d_in[1];
  float* out  = (float*)d_out;
  float* cost = out;                                   // [8]
  float* pi   = out + 8;                               // [8,2048,2048]
  float* C    = out + 8 + (size_t)BB * NN * NN;        // [8,2048,2048]
  float* CT   = pi;  // pi region doubles as C-transposed scratch until finalize

  float* ws    = (float*)d_ws;
  float* u     = ws;                       // [8][2048]
  float* v     = ws + BB * NN;             // [8][2048]
  float* slots = ws + 2 * BB * NN;         // [100][64]
  int*   done  = (int*)(ws + 2 * BB * NN + MAX_ITER * NSLOT);  // [101]

  hipMemsetAsync(d_ws, 0,
                 (size_t)(2 * BB * NN + MAX_ITER * NSLOT + MAX_ITER + 2) * sizeof(float),
                 stream);
  hipMemsetAsync(d_out, 0, 8 * sizeof(float), stream);

  const float emu = (float)(0.1 * log(1.0 / 2048.0 + 1e-8));  // EPS*log(1/N + 1e-8)
  const float enu = emu;                                      // N == M

  dim3 gC(32, 128, BB);
  sq_dist_kernel<<<gC, 256, 0, stream>>>(x, y, C);    // C[b,i,j]
  sq_dist_kernel<<<gC, 256, 0, stream>>>(y, x, CT);   // CT[b,j,i] == C[b,i,j]

  dim3 gd(NN / 4, BB);
  for (int n = 0; n < MAX_ITER; n++) {
    dual_update<true ><<<gd, 256, 0, stream>>>(C,  v, u, slots, done, n, emu);
    dual_update<false><<<gd, 256, 0, stream>>>(CT, u, v, slots, done, n, enu);
  }

  finalize_kernel<<<dim3(32, 32, BB), 256, 0, stream>>>(C, u, v, pi, cost);
}

// Round 2
// 5618.747 us; speedup vs baseline: 1.5996x; 1.5996x over previous
//
#include <hip/hip_runtime.h>
#include <math.h>

#define EPSF     0.1f
#define BB       8
#define NN       2048
#define DIM      32
#define MAX_ITER 100
#define THRESHF  0.1f
#define NSLOT    64
// base-2 domain constants: exp(x) = exp2(x*log2e)
#define C20L2E 28.853900817779268f   // 20*log2(e)  (2/EPS)*log2e
#define C10L2E 14.426950408889634f   // 10*log2(e)  (1/EPS)*log2e
#define LN2F   0.6931471805599453f

typedef __attribute__((ext_vector_type(8))) short  sh8;    // 8 x bf16 (4 VGPRs)
typedef __attribute__((ext_vector_type(4))) float  f32x4;  // MFMA C/D

__device__ __forceinline__ float ex2(float x) { return __builtin_amdgcn_exp2f(x); }
__device__ __forceinline__ float lg2(float x) { return __builtin_amdgcn_logf(x); }

__device__ __forceinline__ unsigned short bf16_rne(float v) {
  unsigned u = __float_as_uint(v);
  unsigned r = (u + 0x7FFFu + ((u >> 16) & 1u)) >> 16;
  return (unsigned short)r;
}

// Split fp32 -> bf16 hi/lo, compute row |.|^2 and initial w2 = 10*log2e*(0 - |.|^2).
// One thread per element; 32 lanes per row (rows are flat b*2048+i).
__global__ __launch_bounds__(256) void prep_kernel(const float* __restrict__ in,
                                                   unsigned short* __restrict__ hi,
                                                   unsigned short* __restrict__ lo,
                                                   float* __restrict__ snorm,
                                                   float* __restrict__ w2init) {
  const int tid = blockIdx.x * 256 + threadIdx.x;
  const int row = tid >> 5, k = tid & 31;
  float val = in[tid];
  unsigned short h = bf16_rne(val);
  float hf = __uint_as_float(((unsigned)h) << 16);
  unsigned short l = bf16_rne(val - hf);
  hi[tid] = h;
  lo[tid] = l;
  float sq = val * val;
#pragma unroll
  for (int off = 1; off < 32; off <<= 1) sq += __shfl_xor(sq, off, 64);
  if (k == 0) {
    snorm[row] = sq;
    w2init[row] = -sq * C10L2E;
  }
  (void)k;
}

// One sweep: self_i = cst + sa_i - EPS*LSE_j( w2_j/log2e + 20*S_ij )  via base-2 online LSE.
// S = A.B^T recomputed with split-bf16 MFMA. WG=256 (4 waves), 32 rows/WG, each wave
// covers a j-quarter (512 cols); 4-way LSE merge in LDS at the end.
template <bool IS_ROW>
__global__ __launch_bounds__(256) void sweep_kernel(const unsigned short* __restrict__ Ah,
                                                    const unsigned short* __restrict__ Al,
                                                    const unsigned short* __restrict__ Bh,
                                                    const unsigned short* __restrict__ Bl,
                                                    const float* __restrict__ sa,
                                                    float* __restrict__ selfD,
                                                    float* __restrict__ wself2,
                                                    const float* __restrict__ woth2,
                                                    float* __restrict__ errSlots,
                                                    int* __restrict__ doneArr,
                                                    int iter, float cst) {
  if (!IS_ROW) {
    if (blockIdx.x == 0 && blockIdx.y == 0 && threadIdx.x == 0) {
      float e = 0.f;
      for (int s2 = 0; s2 < NSLOT; s2++) e += errSlots[iter * NSLOT + s2];
      doneArr[iter + 1] = (doneArr[iter] || (e * 0.125f < THRESHF)) ? 1 : 0;
    }
  }
  if (doneArr[iter]) return;  // frozen (uniform across grid)

  const int b    = blockIdx.y;
  const int i0   = blockIdx.x * 32;
  const int wv   = threadIdx.x >> 6;     // wave -> j quarter
  const int lane = threadIdx.x & 63;
  const int l15  = lane & 15, q = lane >> 4;

  // fixed A fragments: rows i0+l15 (acc0) and i0+16+l15 (acc1), k-chunk q*8
  const size_t arow0 = ((size_t)(b * NN + i0 + l15)) * DIM + q * 8;
  const sh8 a0h = *(const sh8*)(Ah + arow0);
  const sh8 a0l = *(const sh8*)(Al + arow0);
  const sh8 a1h = *(const sh8*)(Ah + arow0 + 16 * DIM);
  const sh8 a1l = *(const sh8*)(Al + arow0 + 16 * DIM);

  float m2[8], ss[8];
#pragma unroll
  for (int r = 0; r < 8; r++) { m2[r] = -1e30f; ss[r] = 0.f; }

  const int jbase = wv * 512;
#pragma unroll 4
  for (int tj = 0; tj < 32; tj++) {
    const int j = jbase + tj * 16;
    const size_t brow = ((size_t)(b * NN + j + l15)) * DIM + q * 8;
    const sh8 bh = *(const sh8*)(Bh + brow);
    const sh8 bl = *(const sh8*)(Bl + brow);
    f32x4 acc0 = {0.f, 0.f, 0.f, 0.f};
    f32x4 acc1 = {0.f, 0.f, 0.f, 0.f};
    acc0 = __builtin_amdgcn_mfma_f32_16x16x32_bf16(a0h, bh, acc0, 0, 0, 0);
    acc1 = __builtin_amdgcn_mfma_f32_16x16x32_bf16(a1h, bh, acc1, 0, 0, 0);
    acc0 = __builtin_amdgcn_mfma_f32_16x16x32_bf16(a0h, bl, acc0, 0, 0, 0);
    acc1 = __builtin_amdgcn_mfma_f32_16x16x32_bf16(a1h, bl, acc1, 0, 0, 0);
    acc0 = __builtin_amdgcn_mfma_f32_16x16x32_bf16(a0l, bh, acc0, 0, 0, 0);
    acc1 = __builtin_amdgcn_mfma_f32_16x16x32_bf16(a1l, bh, acc1, 0, 0, 0);
    const float wj = woth2[b * NN + j + l15];
#pragma unroll
    for (int r = 0; r < 8; r++) {
      const float S = (r < 4) ? acc0[r & 3] : acc1[r & 3];
      const float t = fmaf(S, C20L2E, wj);
      const float mn = fmaxf(m2[r], t);
      ss[r] = ss[r] * ex2(m2[r] - mn) + ex2(t - mn);
      m2[r] = mn;
    }
  }

  // reduce (m,s) across the 16 lanes that share a row
#pragma unroll
  for (int off = 1; off < 16; off <<= 1) {
#pragma unroll
    for (int r = 0; r < 8; r++) {
      const float mo = __shfl_xor(m2[r], off, 64);
      const float so = __shfl_xor(ss[r], off, 64);
      const float mn = fmaxf(m2[r], mo);
      ss[r] = ss[r] * ex2(m2[r] - mn) + so * ex2(mo - mn);
      m2[r] = mn;
    }
  }

  __shared__ float lm[32][4];
  __shared__ float ls[32][4];
  if (l15 == 0) {
#pragma unroll
    for (int r = 0; r < 4; r++) {
      lm[q * 4 + r][wv] = m2[r];      ls[q * 4 + r][wv] = ss[r];
      lm[16 + q * 4 + r][wv] = m2[4 + r]; ls[16 + q * 4 + r][wv] = ss[4 + r];
    }
  }
  __syncthreads();
  if (threadIdx.x < 32) {
    const int row = threadIdx.x;
    float m = lm[row][0], s = ls[row][0];
#pragma unroll
    for (int p = 1; p < 4; p++) {
      const float mo = lm[row][p], so = ls[row][p];
      const float mn = fmaxf(m, mo);
      s = s * ex2(m - mn) + so * ex2(mo - mn);
      m = mn;
    }
    const float lse = (m + lg2(s)) * LN2F;   // natural-log LSE
    const int gi = b * NN + i0 + row;
    const float sav = sa[gi];
    const float nu = cst + sav - EPSF * lse;
    const float old = selfD[gi];
    selfD[gi] = nu;
    wself2[gi] = (nu - sav) * C10L2E;
    if (IS_ROW) {
      float du = fabsf(nu - old);
#pragma unroll
      for (int off = 1; off < 32; off <<= 1) du += __shfl_xor(du, off, 64);
      if (threadIdx.x == 0)
        atomicAdd(&errSlots[iter * NSLOT + (blockIdx.x & (NSLOT - 1))], du);
    }
  }
}

// C = sx_i + sy_j - 2S ; pi = exp2(wu2_i + wv2_j + 20log2e*S) ; cost[b] += pi*C
__global__ __launch_bounds__(256) void finalize_kernel(const unsigned short* __restrict__ xh,
                                                       const unsigned short* __restrict__ xl,
                                                       const unsigned short* __restrict__ yh,
                                                       const unsigned short* __restrict__ yl,
                                                       const float* __restrict__ sx,
                                                       const float* __restrict__ sy,
                                                       const float* __restrict__ wu2,
                                                       const float* __restrict__ wv2,
                                                       float* __restrict__ C,
                                                       float* __restrict__ pi,
                                                       float* __restrict__ cost) {
  const int b  = blockIdx.z;
  const int wv = threadIdx.x >> 6;
  const int lane = threadIdx.x & 63;
  const int l15 = lane & 15, q = lane >> 4;
  const int i0 = blockIdx.y * 128 + wv * 32;
  const int j0 = blockIdx.x * 256;

  const size_t arow0 = ((size_t)(b * NN + i0 + l15)) * DIM + q * 8;
  const sh8 a0h = *(const sh8*)(xh + arow0);
  const sh8 a0l = *(const sh8*)(xl + arow0);
  const sh8 a1h = *(const sh8*)(xh + arow0 + 16 * DIM);
  const sh8 a1l = *(const sh8*)(xl + arow0 + 16 * DIM);

  float sx0[8], wu0[8];
#pragma unroll
  for (int r = 0; r < 8; r++) {
    const int gi = b * NN + i0 + ((r < 4) ? (q * 4 + (r & 3)) : (16 + q * 4 + (r & 3)));
    sx0[r] = sx[gi];
    wu0[r] = wu2[gi];
  }

  float acc = 0.f;
#pragma unroll 2
  for (int tj = 0; tj < 16; tj++) {
    const int j = j0 + tj * 16;
    const size_t brow = ((size_t)(b * NN + j + l15)) * DIM + q * 8;
    const sh8 bh = *(const sh8*)(yh + brow);
    const sh8 bl = *(const sh8*)(yl + brow);
    f32x4 acc0 = {0.f, 0.f, 0.f, 0.f};
    f32x4 acc1 = {0.f, 0.f, 0.f, 0.f};
    acc0 = __builtin_amdgcn_mfma_f32_16x16x32_bf16(a0h, bh, acc0, 0, 0, 0);
    acc1 = __builtin_amdgcn_mfma_f32_16x16x32_bf16(a1h, bh, acc1, 0, 0, 0);
    acc0 = __builtin_amdgcn_mfma_f32_16x16x32_bf16(a0h, bl, acc0, 0, 0, 0);
    acc1 = __builtin_amdgcn_mfma_f32_16x16x32_bf16(a1h, bl, acc1, 0, 0, 0);
    acc0 = __builtin_amdgcn_mfma_f32_16x16x32_bf16(a0l, bh, acc0, 0, 0, 0);
    acc1 = __builtin_amdgcn_mfma_f32_16x16x32_bf16(a1l, bh, acc1, 0, 0, 0);
    const int gj = b * NN + j + l15;
    const float syj = sy[gj];
    const float wvj = wv2[gj];
#pragma unroll
    for (int r = 0; r < 8; r++) {
      const float S = (r < 4) ? acc0[r & 3] : acc1[r & 3];
      const int irow = i0 + ((r < 4) ? (q * 4 + (r & 3)) : (16 + q * 4 + (r & 3)));
      const float Cv = fmaf(-2.f, S, sx0[r] + syj);
      const float p  = ex2(fmaf(S, C20L2E, wu0[r] + wvj));
      const size_t addr = ((size_t)(b * NN + irow)) * NN + j + l15;
      C[addr]  = Cv;
      pi[addr] = p;
      acc = fmaf(p, Cv, acc);
    }
  }
#pragma unroll
  for (int off = 1; off < 64; off <<= 1) acc += __shfl_xor(acc, off, 64);
  __shared__ float red[4];
  if (lane == 0) red[wv] = acc;
  __syncthreads();
  if (threadIdx.x == 0) atomicAdd(&cost[b], red[0] + red[1] + red[2] + red[3]);
}

extern "C" void kernel_launch(void* const* d_in, const int* in_sizes, int n_in,
                              void* d_out, int out_size, void* d_ws, size_t ws_size,
                              hipStream_t stream) {
  const float* x = (const float*)d_in[0];
  const float* y = (const float*)d_in[1];
  float* out  = (float*)d_out;
  float* cost = out;                              // [8]
  float* pi   = out + 8;                          // [8,2048,2048]
  float* C    = out + 8 + (size_t)BB * NN * NN;   // [8,2048,2048]

  float* ws = (float*)d_ws;
  const int BN = BB * NN;                         // 16384
  float* u   = ws;               // [16384]
  float* v   = ws + BN;
  float* wu2 = ws + 2 * BN;
  float* wv2 = ws + 3 * BN;
  float* sx  = ws + 4 * BN;
  float* sy  = ws + 5 * BN;
  float* slots = ws + 6 * BN;                     // [100*64]
  int*   done  = (int*)(ws + 6 * BN + MAX_ITER * NSLOT);  // [101]
  unsigned short* xh = (unsigned short*)(ws + 6 * BN + MAX_ITER * NSLOT + 128);
  const size_t NE = (size_t)BB * NN * DIM;        // 524288
  unsigned short* xl = xh + NE;
  unsigned short* yh = xh + 2 * NE;
  unsigned short* yl = xh + 3 * NE;

  // zero u,v,slots,done (prep rewrites wu2/wv2/sx/sy; bf16 arrays fully rewritten)
  hipMemsetAsync(d_ws, 0, (size_t)(6 * BN + MAX_ITER * NSLOT + 128) * sizeof(float), stream);
  hipMemsetAsync(d_out, 0, 8 * sizeof(float), stream);

  prep_kernel<<<2048, 256, 0, stream>>>(x, xh, xl, sx, wu2);
  prep_kernel<<<2048, 256, 0, stream>>>(y, yh, yl, sy, wv2);

  const float emu = (float)(0.1 * log(1.0 / 2048.0 + 1e-8));
  const float enu = emu;

  dim3 gs(NN / 32, BB);   // 64 x 8 = 512 WGs
  for (int n = 0; n < MAX_ITER; n++) {
    sweep_kernel<true ><<<gs, 256, 0, stream>>>(xh, xl, yh, yl, sx, u, wu2, wv2,
                                                slots, done, n, emu);
    sweep_kernel<false><<<gs, 256, 0, stream>>>(yh, yl, xh, xl, sy, v, wv2, wu2,
                                                slots, done, n, enu);
  }

  finalize_kernel<<<dim3(8, 16, BB), 256, 0, stream>>>(xh, xl, yh, yl, sx, sy,
                                                       wu2, wv2, C, pi, cost);
}